// Round 7
// baseline (1032.104 us; speedup 1.0000x reference)
//
#include <hip/hip_runtime.h>

#define FIN 512
#define FMID 16
#define FOUT 64

typedef __attribute__((ext_vector_type(8))) short bf8_t;    // 8 x bf16 (4 VGPR)
typedef __attribute__((ext_vector_type(4))) float f32x4_t;  // MFMA acc

__device__ __forceinline__ unsigned short f2bf_rne(float f) {
  unsigned u = __float_as_uint(f);
  return (unsigned short)((u + 0x7FFFu + ((u >> 16) & 1u)) >> 16);
}
__device__ __forceinline__ float bf2f(unsigned short h) {
  return __uint_as_float(((unsigned)h) << 16);
}

// ====================== CSR build: bucketed counting sort ======================
// All per-edge atomics hit LDS; device atomics ~2 x nblkA x nbuck one-off
// reservations. Bucket = 256 consecutive nodes (dst>>8);
// packed edge = (src<<8)|(dst&255). csr[] keeps the PACKED form (prop needs
// dst&63 for its 64-node blocks; src = p>>8).

#define CHUNK 8192  // edges per pass-A block

__global__ __launch_bounds__(256) void k_bhist(const int* __restrict__ dst,
                                               int* __restrict__ gtot, int E, int nbuck) {
  __shared__ int hist[1024];
  const int t = threadIdx.x;
  const int base = blockIdx.x * CHUNK;
  const int nloc = min(CHUNK, E - base);
  for (int i = t; i < nbuck; i += 256) hist[i] = 0;
  __syncthreads();
  const int nv = nloc & ~3;
  for (int i = t * 4; i < nv; i += 1024) {
    int4 d = *(const int4*)(dst + base + i);
    atomicAdd(&hist[d.x >> 8], 1);
    atomicAdd(&hist[d.y >> 8], 1);
    atomicAdd(&hist[d.z >> 8], 1);
    atomicAdd(&hist[d.w >> 8], 1);
  }
  if (t == 0)
    for (int i = nv; i < nloc; ++i) atomicAdd(&hist[dst[base + i] >> 8], 1);
  __syncthreads();
  for (int i = t; i < nbuck; i += 256) {
    int c = hist[i];
    if (c) atomicAdd(&gtot[i], c);
  }
}

// single-block exclusive scan of bucket totals (nbuck <= 1024).
__global__ __launch_bounds__(1024) void k_bscan(int* __restrict__ gbase,
                                                int* __restrict__ gcur,
                                                int* __restrict__ rowstart,
                                                int E, int n, int nbuck) {
  __shared__ int sm[1024];
  int t = threadIdx.x;
  int v = (t < nbuck) ? gbase[t] : 0;
  sm[t] = v;
  __syncthreads();
  for (int off = 1; off < 1024; off <<= 1) {
    int a = (t >= off) ? sm[t - off] : 0;
    __syncthreads();
    sm[t] += a;
    __syncthreads();
  }
  int excl = sm[t] - v;
  if (t < nbuck) {
    gbase[t] = excl;
    gcur[t] = excl;
  }
  if (t == 0) {
    gbase[nbuck] = E;
    rowstart[n] = E;
  }
}

// Scatter edges into bucket-ordered packed[]: per-block LDS histogram, one
// device atomic per (block,bucket) segment reservation, LDS cursor placement.
__global__ __launch_bounds__(256) void k_bucketA(const int* __restrict__ src,
                                                 const int* __restrict__ dst,
                                                 int* __restrict__ gcur,
                                                 int* __restrict__ packed,
                                                 int E, int nbuck) {
  __shared__ int hist[1024];
  const int t = threadIdx.x;
  const int base = blockIdx.x * CHUNK;
  const int nloc = min(CHUNK, E - base);
  for (int i = t; i < nbuck; i += 256) hist[i] = 0;
  __syncthreads();
  const int nv = nloc & ~3;
  for (int i = t * 4; i < nv; i += 1024) {
    int4 d = *(const int4*)(dst + base + i);
    atomicAdd(&hist[d.x >> 8], 1);
    atomicAdd(&hist[d.y >> 8], 1);
    atomicAdd(&hist[d.z >> 8], 1);
    atomicAdd(&hist[d.w >> 8], 1);
  }
  if (t == 0)
    for (int i = nv; i < nloc; ++i) atomicAdd(&hist[dst[base + i] >> 8], 1);
  __syncthreads();
  for (int i = t; i < nbuck; i += 256) {
    int c = hist[i];
    hist[i] = c ? atomicAdd(&gcur[i], c) : 0;  // hist becomes global cursor
  }
  __syncthreads();
  for (int i = t * 4; i < nv; i += 1024) {
    int4 d = *(const int4*)(dst + base + i);
    int4 s = *(const int4*)(src + base + i);
    int p0 = atomicAdd(&hist[d.x >> 8], 1);
    int p1 = atomicAdd(&hist[d.y >> 8], 1);
    int p2 = atomicAdd(&hist[d.z >> 8], 1);
    int p3 = atomicAdd(&hist[d.w >> 8], 1);
    packed[p0] = (s.x << 8) | (d.x & 255);
    packed[p1] = (s.y << 8) | (d.y & 255);
    packed[p2] = (s.z << 8) | (d.z & 255);
    packed[p3] = (s.w << 8) | (d.w & 255);
  }
  if (t == 0)
    for (int i = nv; i < nloc; ++i) {
      int d = dst[base + i], s = src[base + i];
      int p = atomicAdd(&hist[d >> 8], 1);
      packed[p] = (s << 8) | (d & 255);
    }
}

// One block per bucket: count 256 node-counters in LDS, block-scan, write
// rowstart + dis, then place PACKED entries into node-sorted csr.
__global__ __launch_bounds__(256) void k_bucketB(const int* __restrict__ packed,
                                                 const int* __restrict__ gbase,
                                                 int* __restrict__ rowstart,
                                                 float* __restrict__ dis,
                                                 int* __restrict__ csr, int n) {
  __shared__ int cnt[256];
  __shared__ int cur[256];
  const int b = blockIdx.x;
  const int t = threadIdx.x;
  const int beg = gbase[b], end = gbase[b + 1];
  cnt[t] = 0;
  __syncthreads();
  for (int i = beg + t; i < end; i += 256) atomicAdd(&cnt[packed[i] & 255], 1);
  __syncthreads();
  int v = cnt[t];
  cur[t] = v;
  __syncthreads();
  for (int off = 1; off < 256; off <<= 1) {
    int a = (t >= off) ? cur[t - off] : 0;
    __syncthreads();
    cur[t] += a;
    __syncthreads();
  }
  int excl = cur[t] - v;  // local exclusive prefix within bucket
  int node = (b << 8) + t;
  if (node < n) {
    rowstart[node] = beg + excl;
    dis[node] = rsqrtf((float)v + 1.0f);  // +1 self-loop
  }
  __syncthreads();
  cur[t] = beg + excl;  // cursor for placement
  __syncthreads();
  for (int i = beg + t; i < end; i += 256) {
    int p = packed[i];
    int pos = atomicAdd(&cur[p & 255], 1);
    csr[pos] = p;  // keep packed: (src<<8)|(dst&255)
  }
}

// ============================ dense layers ============================

// hs[node,0:16] = (x[node,0:512] @ W1) * dis[node] via mfma_f32_16x16x32_bf16.
// Split-bf16 for fp32 accuracy; W1 pre-split hi/lo into B-frag order in LDS.
__global__ __launch_bounds__(256) void k_gemm1(const float* __restrict__ x,
                                               const float* __restrict__ W1,
                                               const float* __restrict__ dis,
                                               float* __restrict__ hs, int n,
                                               int ntiles) {
  __shared__ short wb_hi[16][64][8];  // 16 KB: B-frag hi, [kstep][lane][i]
  __shared__ short wb_lo[16][64][8];  // 16 KB: B-frag lo
  for (int e = threadIdx.x; e < FIN * FMID; e += 256) {
    int k = e >> 4, j = e & 15;
    int ks = k >> 5, kk = k & 31;
    int L = ((kk >> 3) << 4) + j, i = kk & 7;
    float f = W1[e];
    unsigned short h = f2bf_rne(f);
    wb_hi[ks][L][i] = (short)h;
    wb_lo[ks][L][i] = (short)f2bf_rne(f - bf2f(h));
  }
  __syncthreads();
  const int lane = threadIdx.x & 63;
  const int wid  = threadIdx.x >> 6;
  const int rloc = lane & 15;  // A-row / D-col
  const int q    = lane >> 4;  // k-subchunk / D-row-quad
  for (int tile = blockIdx.x * 4 + wid; tile < ntiles; tile += gridDim.x * 4) {
    int row = tile * 16 + rloc;
    const float4* xr = (const float4*)(x + (size_t)(row < n ? row : n - 1) * FIN);
    f32x4_t acc = {0.f, 0.f, 0.f, 0.f};
#pragma unroll 4
    for (int ks = 0; ks < 16; ++ks) {
      float4 v0 = xr[ks * 8 + q * 2];
      float4 v1 = xr[ks * 8 + q * 2 + 1];
      float fv[8] = {v0.x, v0.y, v0.z, v0.w, v1.x, v1.y, v1.z, v1.w};
      bf8_t ah, al;
#pragma unroll
      for (int i = 0; i < 8; ++i) {
        unsigned short h = f2bf_rne(fv[i]);
        ah[i] = (short)h;
        al[i] = (short)f2bf_rne(fv[i] - bf2f(h));
      }
      bf8_t bh = *(const bf8_t*)&wb_hi[ks][lane][0];
      bf8_t bl = *(const bf8_t*)&wb_lo[ks][lane][0];
      acc = __builtin_amdgcn_mfma_f32_16x16x32_bf16(ah, bh, acc, 0, 0, 0);
      acc = __builtin_amdgcn_mfma_f32_16x16x32_bf16(al, bh, acc, 0, 0, 0);
      acc = __builtin_amdgcn_mfma_f32_16x16x32_bf16(ah, bl, acc, 0, 0, 0);
    }
    int nb = tile * 16 + q * 4;
#pragma unroll
    for (int r = 0; r < 4; ++r) {
      int node = nb + r;
      if (node < n) hs[(size_t)node * FMID + rloc] = acc[r] * dis[node];
    }
  }
}

// Edge-parallel CSR propagation with LDS accumulation. Block = 64 consecutive
// nodes (edge range contiguous in the dst-sorted csr). acc[64][16] is
// initialized with the self-loop term, then edges are processed edge-parallel:
// 4 lanes/edge (c = feature quad), 64 edges per block-step, 4-deep unrolled
// (4 independent gathers in flight per lane); features accumulate via native
// LDS atomicAdd (ds_add_f32). Replaces the node-parallel k_prop_csr whose
// serial remainder loop + degree-imbalance divergence + shuffle reduce cost
// ~2x the gather floor (~140 us/layer). Flush = coalesced float4 write with
// fused dd/bias/ReLU epilogue.
//   raw[d][j] = dis[d] * (hs[d][j] + sum_{s in N(d)} hs[s][j])
// RELU=true (layer 1): out = relu(raw + bias) * dis[d]   (pre-scaled for L2)
// RELU=false (layer 2): out = raw                        (k_out adds b2)
template <bool RELU>
__global__ __launch_bounds__(256) void k_prop_ep(const float* __restrict__ hs,
                                                 const int* __restrict__ rowstart,
                                                 const int* __restrict__ csrp,
                                                 const float* __restrict__ dis,
                                                 const float* __restrict__ bias,
                                                 float* __restrict__ outp, int n) {
  __shared__ float acc[64][16];  // 4 KB
  const int t = threadIdx.x;
  const int node0 = blockIdx.x * 64;
  const int nl = t >> 2;  // local node for init/flush
  const int c  = t & 3;   // feature quad
  const int node = node0 + nl;
  float4 selfv = make_float4(0.f, 0.f, 0.f, 0.f);
  if (node < n) selfv = ((const float4*)hs)[(size_t)node * 4 + c];
  *(float4*)&acc[nl][c * 4] = selfv;
  __syncthreads();
  const int beg = rowstart[node0];
  const int end = rowstart[min(node0 + 64, n)];
  const int es = t >> 2;  // edge slot 0..63
  for (int base = beg; base < end; base += 256) {
#pragma unroll
    for (int u = 0; u < 4; ++u) {
      int i = base + u * 64 + es;
      if (i < end) {
        int p = csrp[i];
        int s = p >> 8;
        int dl = p & 63;
        float4 v = ((const float4*)hs)[(size_t)s * 4 + c];
        atomicAdd(&acc[dl][c * 4 + 0], v.x);
        atomicAdd(&acc[dl][c * 4 + 1], v.y);
        atomicAdd(&acc[dl][c * 4 + 2], v.z);
        atomicAdd(&acc[dl][c * 4 + 3], v.w);
      }
    }
  }
  __syncthreads();
  if (node < n) {
    float dd = dis[node];
    float4 a = *(const float4*)&acc[nl][c * 4];
    float4 r;
    r.x = dd * a.x; r.y = dd * a.y; r.z = dd * a.z; r.w = dd * a.w;
    if (RELU) {
      float4 bb = ((const float4*)bias)[c];
      r.x = fmaxf(r.x + bb.x, 0.f) * dd;
      r.y = fmaxf(r.y + bb.y, 0.f) * dd;
      r.z = fmaxf(r.z + bb.z, 0.f) * dd;
      r.w = fmaxf(r.w + bb.w, 0.f) * dd;
    }
    ((float4*)outp)[(size_t)node * 4 + c] = r;
  }
}

// out[node, 0:64] = log_softmax(a2[node, 0:16] @ W2 + b2). One wave per node.
__global__ __launch_bounds__(256) void k_out(const float* __restrict__ a2,
                                             const float* __restrict__ W2,
                                             const float* __restrict__ b2,
                                             float* __restrict__ out, int n) {
  __shared__ float w[FMID * FOUT];  // 4 KB
  for (int idx = threadIdx.x; idx < FMID * FOUT; idx += 256) w[idx] = W2[idx];
  __syncthreads();
  const int lane = threadIdx.x & 63;
  const int node = blockIdx.x * 4 + (threadIdx.x >> 6);
  if (node >= n) return;
  const float4* ar4 = (const float4*)(a2 + (size_t)node * FMID);
  float4 q0 = ar4[0], q1 = ar4[1], q2 = ar4[2], q3 = ar4[3];
  float av[16] = {q0.x, q0.y, q0.z, q0.w, q1.x, q1.y, q1.z, q1.w,
                  q2.x, q2.y, q2.z, q2.w, q3.x, q3.y, q3.z, q3.w};
  float o = b2[lane];
#pragma unroll
  for (int k = 0; k < FMID; ++k) o += av[k] * w[k * FOUT + lane];
  float m = o;
#pragma unroll
  for (int off = 32; off >= 1; off >>= 1) m = fmaxf(m, __shfl_xor(m, off));
  float e = __expf(o - m);
  float s = e;
#pragma unroll
  for (int off = 32; off >= 1; off >>= 1) s += __shfl_xor(s, off);
  out[(size_t)node * FOUT + lane] = o - m - __logf(s);
}

// ==================== fallback (atomic path, small ws) ====================

__global__ void k_deg_init(float* __restrict__ deg, int n) {
  int i = blockIdx.x * blockDim.x + threadIdx.x;
  if (i < n) deg[i] = 1.0f;
}
__global__ void k_deg_edges(const int* __restrict__ dst, float* __restrict__ deg, int E) {
  int e = blockIdx.x * blockDim.x + threadIdx.x;
  if (e < E) atomicAdd(&deg[dst[e]], 1.0f);
}
__global__ void k_deg_finish(float* __restrict__ deg, int n) {
  int i = blockIdx.x * blockDim.x + threadIdx.x;
  if (i < n) deg[i] = rsqrtf(deg[i]);
}
__global__ void k_selfloop_s(const float* __restrict__ hs, const float* __restrict__ dis,
                             float* __restrict__ a, int total16) {
  int t = blockIdx.x * blockDim.x + threadIdx.x;
  if (t < total16) a[t] = hs[t] * dis[t >> 4];
}
__global__ void k_prop_atomic(const float* __restrict__ hs, const int* __restrict__ src,
                              const int* __restrict__ dst, const float* __restrict__ dis,
                              float* __restrict__ outp, int E) {
  int t = blockIdx.x * blockDim.x + threadIdx.x;
  int e = t >> 4;
  if (e >= E) return;
  int jj = t & 15;
  int s = src[e], d = dst[e];
  atomicAdd(&outp[(size_t)d * FMID + jj], hs[(size_t)s * FMID + jj] * dis[d]);
}
__global__ void k_bias_relu_s(float* __restrict__ a, const float* __restrict__ b,
                              const float* __restrict__ dis, int total16) {
  int t = blockIdx.x * blockDim.x + threadIdx.x;
  if (t < total16) {
    float v = a[t] + b[t & 15];
    a[t] = (v > 0.f ? v : 0.f) * dis[t >> 4];
  }
}

// ============================ launcher ============================

extern "C" void kernel_launch(void* const* d_in, const int* in_sizes, int n_in,
                              void* d_out, int out_size, void* d_ws, size_t ws_size,
                              hipStream_t stream) {
  const float* x  = (const float*)d_in[0];
  const int* edge = (const int*)d_in[1];
  const float* W1 = (const float*)d_in[2];
  const float* b1 = (const float*)d_in[3];
  const float* W2 = (const float*)d_in[4];
  const float* b2 = (const float*)d_in[5];
  float* out = (float*)d_out;

  const int N = in_sizes[0] / FIN;   // 100000
  const int E = in_sizes[1] / 2;     // 3200000
  const int* src = edge;
  const int* dst = edge + E;

  const int T = 256;
  const int t16n = N * FMID;
  const int ntiles = (N + 15) / 16;  // 6250
  int gblocks = (ntiles + 3) / 4;
  if (gblocks > 2048) gblocks = 2048;

  const int nbuck = (N + 255) >> 8;        // 391
  const int nblkA = (E + CHUNK - 1) / CHUNK;
  const int nblk64 = (N + 63) / 64;        // 1563

  // CSR-path workspace (floats): dis[N] | buf0[16N] | buf1[16N], then ints:
  // rowstart[N+1] | gbase[nbuck+1] | gcur[nbuck] | csr[E].
  // packed[E] aliases buf0..buf1 (needs E <= 32N); dead before k_gemm1.
  size_t need_csr = ((size_t)33 * N + (size_t)(N + 1) + (size_t)(2 * nbuck + 1) +
                     (size_t)E) * 4;
  bool new_ok = (ws_size >= need_csr) && ((size_t)E <= (size_t)32 * N) &&
                (nbuck <= 1024) && ((size_t)N < (1u << 23));

  if (new_ok) {
    float* fbase = (float*)d_ws;
    float* dis  = fbase;
    float* buf0 = fbase + (size_t)N;         // hs, later a2
    float* buf1 = fbase + 17 * (size_t)N;    // a1 (scaled)
    int* packed   = (int*)buf0;              // aliases buf0+buf1 (E ints)
    int* ibase    = (int*)(fbase + 33 * (size_t)N);
    int* rowstart = ibase;                   // N+1
    int* gbase    = ibase + (size_t)N + 1;   // nbuck+1 (totals -> excl prefix)
    int* gcur     = gbase + nbuck + 1;       // nbuck
    int* csr      = gcur + nbuck;            // E (packed entries)

    hipMemsetAsync(gbase, 0, (size_t)(nbuck + 1) * sizeof(int), stream);
    k_bhist  <<<nblkA, T, 0, stream>>>(dst, gbase, E, nbuck);
    k_bscan  <<<1, 1024, 0, stream>>>(gbase, gcur, rowstart, E, N, nbuck);
    k_bucketA<<<nblkA, T, 0, stream>>>(src, dst, gcur, packed, E, nbuck);
    k_bucketB<<<nbuck, T, 0, stream>>>(packed, gbase, rowstart, dis, csr, N);

    k_gemm1  <<<gblocks, T, 0, stream>>>(x, W1, dis, buf0, N, ntiles);

    k_prop_ep<true>  <<<nblk64, T, 0, stream>>>(buf0, rowstart, csr, dis, b1, buf1, N);
    k_prop_ep<false> <<<nblk64, T, 0, stream>>>(buf1, rowstart, csr, dis, b1, buf0, N);
    k_out    <<<(N + 3) / 4, T, 0, stream>>>(buf0, W2, b2, out, N);
  } else {
    // atomic fallback: dis[N] | hs[16N] | a1[16N] | a2[16N] (~19.6 MB)
    float* f   = (float*)d_ws;
    float* dis = f;
    float* hs  = f + (size_t)N;
    float* a1  = f + 17 * (size_t)N;
    float* a2  = f + 33 * (size_t)N;
    const long te = (long)E * FMID;

    k_deg_init  <<<(N + T - 1) / T, T, 0, stream>>>(dis, N);
    k_deg_edges <<<(E + T - 1) / T, T, 0, stream>>>(dst, dis, E);
    k_deg_finish<<<(N + T - 1) / T, T, 0, stream>>>(dis, N);

    k_gemm1     <<<gblocks, T, 0, stream>>>(x, W1, dis, hs, N, ntiles);

    k_selfloop_s<<<(t16n + T - 1) / T, T, 0, stream>>>(hs, dis, a1, t16n);
    k_prop_atomic<<<(int)((te + T - 1) / T), T, 0, stream>>>(hs, src, dst, dis, a1, E);
    k_bias_relu_s<<<(t16n + T - 1) / T, T, 0, stream>>>(a1, b1, dis, t16n);

    k_selfloop_s<<<(t16n + T - 1) / T, T, 0, stream>>>(a1, dis, a2, t16n);
    k_prop_atomic<<<(int)((te + T - 1) / T), T, 0, stream>>>(a1, src, dst, dis, a2, E);

    k_out       <<<(N + 3) / 4, T, 0, stream>>>(a2, W2, b2, out, N);
  }
}